// Round 2
// baseline (21938.547 us; speedup 1.0000x reference)
//
#include <hip/hip_runtime.h>
#include <stdint.h>

#define NN   2048
#define TTT  512
#define NT   (NN * TTT)          /* 1048576 rows */
#define NTM  (NN * (TTT - 1))    /* 1046528 rows */
#define SLOPE 0.01f
#define BN_EPS 1e-5f

typedef unsigned int uint;

__device__ __forceinline__ float bf2f(uint16_t u) {
    union { uint u32; float f; } v; v.u32 = ((uint)u) << 16; return v.f;
}
__device__ __forceinline__ uint16_t f2bf(float f) {
    union { float f; uint u; } v; v.f = f;
    uint r = v.u + 0x7FFFu + ((v.u >> 16) & 1u);   // RTNE
    return (uint16_t)(r >> 16);
}

// ---- dtype-flexible loads/stores (flag: true = fp32 buffers, false = bf16) ----
__device__ __forceinline__ void load16bf(const uint16_t* p, float* f) {
    const uint4* q = (const uint4*)p;
    uint4 a = q[0], b = q[1];
    uint w[8] = {a.x, a.y, a.z, a.w, b.x, b.y, b.z, b.w};
#pragma unroll
    for (int i = 0; i < 8; i++) {
        union { uint u; float f; } lo, hi;
        lo.u = w[i] << 16; hi.u = w[i] & 0xFFFF0000u;
        f[2 * i] = lo.f; f[2 * i + 1] = hi.f;
    }
}
__device__ __forceinline__ void loadrow16(const void* x, size_t elt, bool f32, float* f) {
    if (f32) {
        const float4* q = (const float4*)((const float*)x + elt);
        float4 a = q[0], b = q[1], c = q[2], d = q[3];
        f[0]=a.x; f[1]=a.y; f[2]=a.z; f[3]=a.w;
        f[4]=b.x; f[5]=b.y; f[6]=b.z; f[7]=b.w;
        f[8]=c.x; f[9]=c.y; f[10]=c.z; f[11]=c.w;
        f[12]=d.x; f[13]=d.y; f[14]=d.z; f[15]=d.w;
    } else {
        load16bf((const uint16_t*)x + elt, f);
    }
}
__device__ __forceinline__ void loadrow32(const void* x, size_t elt, bool f32, float* f) {
    loadrow16(x, elt, f32, f);
    loadrow16(x, elt + 16, f32, f + 16);
}
__device__ __forceinline__ void storerow32(void* out, size_t elt, bool f32, const float* f) {
    if (f32) {
        float4* q = (float4*)((float*)out + elt);
#pragma unroll
        for (int i = 0; i < 8; i++)
            q[i] = make_float4(f[4*i], f[4*i+1], f[4*i+2], f[4*i+3]);
    } else {
        uint w[16];
#pragma unroll
        for (int i = 0; i < 16; i++)
            w[i] = (uint)f2bf(f[2*i]) | ((uint)f2bf(f[2*i+1]) << 16);
        uint4* q = (uint4*)((uint16_t*)out + elt);
        q[0] = make_uint4(w[0], w[1], w[2], w[3]);
        q[1] = make_uint4(w[4], w[5], w[6], w[7]);
        q[2] = make_uint4(w[8], w[9], w[10], w[11]);
        q[3] = make_uint4(w[12], w[13], w[14], w[15]);
    }
}
__device__ __forceinline__ float wval(const void* W, int i, bool f32) {
    return f32 ? ((const float*)W)[i] : bf2f(((const uint16_t*)W)[i]);
}

// h[j] += sum_i W[i*32+j] * in[i]   (W in LDS, fp32)
template <int K>
__device__ __forceinline__ void dense(const float* W, const float* in, float* h) {
#pragma unroll
    for (int i = 0; i < K; i++) {
        float x = in[i];
        const float4* w4 = (const float4*)(W + i * 32);
#pragma unroll
        for (int j = 0; j < 8; j++) {
            float4 w = w4[j];
            h[4*j+0] = fmaf(w.x, x, h[4*j+0]);
            h[4*j+1] = fmaf(w.y, x, h[4*j+1]);
            h[4*j+2] = fmaf(w.z, x, h[4*j+2]);
            h[4*j+3] = fmaf(w.w, x, h[4*j+3]);
        }
    }
}
__device__ __forceinline__ void lrelu32(float* h) {
#pragma unroll
    for (int j = 0; j < 32; j++) h[j] = fmaxf(h[j], h[j] * SLOPE);
}

// ---------------- dtype detect: 1 = fp32, 0 = bf16 ----------------
// Low 16 bits of each 32-bit word: for bf16 buffers this is an even-index
// bf16 element (exponent ~126 for N(0,1) data); for fp32 buffers these are
// mantissa bits (uniform). Majority vote over 64 words.
__global__ void detect_kernel(const uint* __restrict__ x, int* __restrict__ flag) {
    __shared__ int cnt;
    if (threadIdx.x == 0) cnt = 0;
    __syncthreads();
    uint w = x[threadIdx.x];
    uint e = (w >> 7) & 0xFFu;
    if (e >= 110u && e <= 134u) atomicAdd(&cnt, 1);
    __syncthreads();
    if (threadIdx.x == 0) flag[0] = (cnt < 32) ? 1 : 0;
}

// ---------------- edge kernels: one per branch ----------------
// BRANCH 0: inplace [x_t, x_t, 0]      rows NT,  t = r&511
// BRANCH 1: fwd     [x_t, x_{t-1}, +1] rows NTM, t = q+1
// BRANCH 2: bwd     [x_t, x_{t+1}, -1] rows NTM, t = q
template <int BRANCH>
__global__ __launch_bounds__(256) void edge_kernel(
    const void* __restrict__ x,
    const void* __restrict__ W1, const void* __restrict__ b1,
    const void* __restrict__ W2, const void* __restrict__ b2,
    const void* __restrict__ W3, const void* __restrict__ b3,
    const int* __restrict__ flag, float* __restrict__ gstats)
{
    __shared__ __align__(16) float sW1[33 * 32];
    __shared__ __align__(16) float sW2[32 * 32];
    __shared__ __align__(16) float sW3[32 * 32];
    __shared__ float sB1[32], sB2[32], sB3[32];
    __shared__ float sSt[64];
    const int tid = threadIdx.x;
    const bool f32 = flag[0] != 0;

    if (BRANCH == 0) {
        for (int i = tid; i < 512; i += 256) sW1[i] = wval(W1, i, f32) + wval(W1, 512 + i, f32);
    } else {
        for (int i = tid; i < 1056; i += 256) sW1[i] = wval(W1, i, f32);
    }
    for (int i = tid; i < 1024; i += 256) sW2[i] = wval(W2, i, f32);
    for (int i = tid; i < 1024; i += 256) sW3[i] = wval(W3, i, f32);
    if (tid < 32) { sB1[tid] = wval(b1, tid, f32); sB2[tid] = wval(b2, tid, f32); sB3[tid] = wval(b3, tid, f32); }
    if (tid < 64) sSt[tid] = 0.f;
    __syncthreads();

    constexpr uint NROWS = (BRANCH == 0) ? (uint)NT : (uint)NTM;
    float accs[32], accq[32];
#pragma unroll
    for (int j = 0; j < 32; j++) { accs[j] = 0.f; accq[j] = 0.f; }

    for (uint r = blockIdx.x * 256u + (uint)tid; r < NROWS; r += gridDim.x * 256u) {
        uint n, t, tn;
        if (BRANCH == 0) { n = r >> 9; t = r & 511u; tn = t; }
        else {
            n = r / 511u; uint q = r - n * 511u;
            if (BRANCH == 1) { t = q + 1u; tn = q; } else { t = q; tn = q + 1u; }
        }
        float xt[16]; loadrow16(x, (size_t)(((n << 9) + t)) << 4, f32, xt);
        float h1[32];
#pragma unroll
        for (int j = 0; j < 32; j++) {
            float v = sB1[j];
            if (BRANCH == 1) v += sW1[1024 + j];
            if (BRANCH == 2) v -= sW1[1024 + j];
            h1[j] = v;
        }
        if (BRANCH == 0) {
            dense<16>(sW1, xt, h1);                  // combined A+B halves
        } else {
            dense<16>(sW1, xt, h1);                  // A half (rows 0..15)
            float xn[16]; loadrow16(x, (size_t)(((n << 9) + tn)) << 4, f32, xn);
            dense<16>(sW1 + 512, xn, h1);            // B half (rows 16..31)
        }
        lrelu32(h1);
        float h2[32];
#pragma unroll
        for (int j = 0; j < 32; j++) h2[j] = sB2[j];
        dense<32>(sW2, h1, h2);
        lrelu32(h2);
        float h3[32];
#pragma unroll
        for (int j = 0; j < 32; j++) h3[j] = sB3[j];
        dense<32>(sW3, h2, h3);
#pragma unroll
        for (int j = 0; j < 32; j++) { accs[j] += h3[j]; accq[j] = fmaf(h3[j], h3[j], accq[j]); }
    }
#pragma unroll
    for (int j = 0; j < 32; j++) { atomicAdd(&sSt[j], accs[j]); atomicAdd(&sSt[32 + j], accq[j]); }
    __syncthreads();
    if (tid < 64) atomicAdd(&gstats[tid], sSt[tid]);
}

// ---------------- node kernel (recomputes all three edge branches) ----------------
__global__ __launch_bounds__(256) void node_kernel(
    const void* __restrict__ x,
    const void* __restrict__ eW1, const void* __restrict__ eb1,
    const void* __restrict__ eW2, const void* __restrict__ eb2,
    const void* __restrict__ eW3, const void* __restrict__ eb3,
    const void* __restrict__ egamma, const void* __restrict__ ebeta,
    const void* __restrict__ nW1, const void* __restrict__ nb1,
    const void* __restrict__ nW2, const void* __restrict__ nb2,
    const void* __restrict__ nW3, const void* __restrict__ nb3,
    const int* __restrict__ flag,
    const float* __restrict__ gstats_edge, float* __restrict__ gstats_node,
    void* __restrict__ out)
{
    __shared__ __align__(16) float sNW1[1024];
    __shared__ __align__(16) float sNW2[1024];
    __shared__ __align__(16) float sNW3[1024];
    __shared__ float sNB1[32], sNB2[32], sNB3[32];
    __shared__ __align__(16) float sEW1[33 * 32];
    __shared__ __align__(16) float sEW2[1024];
    __shared__ __align__(16) float sEW3[1024];
    __shared__ float sEB1[32], sEB2[32], sEB3[32];
    __shared__ float sAff[192];   // per branch: [0..31]=scale, [32..63]=shift
    __shared__ float sSt[64];
    const int tid = threadIdx.x;
    const bool f32 = flag[0] != 0;

    for (int i = tid; i < 1024; i += 256) {
        sNW1[i] = wval(nW1, i, f32); sNW2[i] = wval(nW2, i, f32); sNW3[i] = wval(nW3, i, f32);
        sEW2[i] = wval(eW2, i, f32); sEW3[i] = wval(eW3, i, f32);
    }
    for (int i = tid; i < 1056; i += 256) sEW1[i] = wval(eW1, i, f32);
    if (tid < 32) {
        sNB1[tid] = wval(nb1, tid, f32); sNB2[tid] = wval(nb2, tid, f32); sNB3[tid] = wval(nb3, tid, f32);
        sEB1[tid] = wval(eb1, tid, f32); sEB2[tid] = wval(eb2, tid, f32); sEB3[tid] = wval(eb3, tid, f32);
        float g = wval(egamma, tid, f32), be = wval(ebeta, tid, f32);
#pragma unroll
        for (int br = 0; br < 3; br++) {
            float cnt = (br == 0) ? (float)NT : (float)NTM;
            float s = gstats_edge[br * 64 + tid], q = gstats_edge[br * 64 + 32 + tid];
            float mu = s / cnt;
            float var = q / cnt - mu * mu;
            float sc = g * rsqrtf(var + BN_EPS);
            sAff[br * 64 + tid] = sc;
            sAff[br * 64 + 32 + tid] = be - mu * sc;
        }
    }
    if (tid < 64) sSt[tid] = 0.f;
    __syncthreads();

    float accs[32], accq[32];
#pragma unroll
    for (int j = 0; j < 32; j++) { accs[j] = 0.f; accq[j] = 0.f; }

    for (uint r = blockIdx.x * 256u + (uint)tid; r < (uint)NT; r += gridDim.x * 256u) {
        uint n = r >> 9, t = r & 511u;
        float agg[32], v[32], xt[16];
        loadrow16(x, (size_t)(((n << 9) + t)) << 4, f32, xt);

        // inplace branch [x_t, x_t, 0]
        {
            float h1[32];
#pragma unroll
            for (int j = 0; j < 32; j++) h1[j] = sEB1[j];
            dense<16>(sEW1, xt, h1);
            dense<16>(sEW1 + 512, xt, h1);
            lrelu32(h1);
            float h2[32];
#pragma unroll
            for (int j = 0; j < 32; j++) h2[j] = sEB2[j];
            dense<32>(sEW2, h1, h2);
            lrelu32(h2);
#pragma unroll
            for (int j = 0; j < 32; j++) v[j] = sEB3[j];
            dense<32>(sEW3, h2, v);
        }
#pragma unroll
        for (int j = 0; j < 32; j++) agg[j] = fmaf(sAff[j], v[j], sAff[32 + j]);

        // fwd branch [x_t, x_{t-1}, +1], valid t>=1
        if (t > 0u) {
            float xp[16]; loadrow16(x, (size_t)(((n << 9) + t - 1u)) << 4, f32, xp);
            float h1[32];
#pragma unroll
            for (int j = 0; j < 32; j++) h1[j] = sEB1[j] + sEW1[1024 + j];
            dense<16>(sEW1, xt, h1);
            dense<16>(sEW1 + 512, xp, h1);
            lrelu32(h1);
            float h2[32];
#pragma unroll
            for (int j = 0; j < 32; j++) h2[j] = sEB2[j];
            dense<32>(sEW2, h1, h2);
            lrelu32(h2);
#pragma unroll
            for (int j = 0; j < 32; j++) v[j] = sEB3[j];
            dense<32>(sEW3, h2, v);
#pragma unroll
            for (int j = 0; j < 32; j++) agg[j] += fmaf(sAff[64 + j], v[j], sAff[96 + j]);
        }
        // bwd branch [x_t, x_{t+1}, -1], valid t<=510
        if (t < 511u) {
            float xn[16]; loadrow16(x, (size_t)(((n << 9) + t + 1u)) << 4, f32, xn);
            float h1[32];
#pragma unroll
            for (int j = 0; j < 32; j++) h1[j] = sEB1[j] - sEW1[1024 + j];
            dense<16>(sEW1, xt, h1);
            dense<16>(sEW1 + 512, xn, h1);
            lrelu32(h1);
            float h2[32];
#pragma unroll
            for (int j = 0; j < 32; j++) h2[j] = sEB2[j];
            dense<32>(sEW2, h1, h2);
            lrelu32(h2);
#pragma unroll
            for (int j = 0; j < 32; j++) v[j] = sEB3[j];
            dense<32>(sEW3, h2, v);
#pragma unroll
            for (int j = 0; j < 32; j++) agg[j] += fmaf(sAff[128 + j], v[j], sAff[160 + j]);
        }

        // node MLP
        float g1[32];
#pragma unroll
        for (int j = 0; j < 32; j++) g1[j] = sNB1[j];
        dense<32>(sNW1, agg, g1);
        lrelu32(g1);
        float g2[32];
#pragma unroll
        for (int j = 0; j < 32; j++) g2[j] = sNB2[j];
        dense<32>(sNW2, g1, g2);
        lrelu32(g2);
        float g3[32];
#pragma unroll
        for (int j = 0; j < 32; j++) g3[j] = sNB3[j];
        dense<32>(sNW3, g2, g3);

        storerow32(out, (size_t)r * 32u, f32, g3);
#pragma unroll
        for (int j = 0; j < 32; j++) { accs[j] += g3[j]; accq[j] = fmaf(g3[j], g3[j], accq[j]); }
    }
#pragma unroll
    for (int j = 0; j < 32; j++) { atomicAdd(&sSt[j], accs[j]); atomicAdd(&sSt[32 + j], accq[j]); }
    __syncthreads();
    if (tid < 64) atomicAdd(&gstats_node[tid], sSt[tid]);
}

// ---------------- finalize: in-place BN affine on out ----------------
__global__ __launch_bounds__(256) void finalize_kernel(
    const float* __restrict__ gstats_node,
    const void* __restrict__ ngamma, const void* __restrict__ nbeta,
    const int* __restrict__ flag, void* __restrict__ out)
{
    __shared__ float sc[32], sh[32];
    const int tid = threadIdx.x;
    const bool f32 = flag[0] != 0;
    if (tid < 32) {
        float s = gstats_node[tid], q = gstats_node[32 + tid];
        float mu = s / (float)NT;
        float var = q / (float)NT - mu * mu;
        float k = wval(ngamma, tid, f32) * rsqrtf(var + BN_EPS);
        sc[tid] = k; sh[tid] = wval(nbeta, tid, f32) - mu * k;
    }
    __syncthreads();
    uint r = blockIdx.x * 256u + (uint)tid;
    if (r < (uint)NT) {
        float v[32]; loadrow32(out, (size_t)r * 32u, f32, v);
        float o[32];
#pragma unroll
        for (int j = 0; j < 32; j++) o[j] = fmaf(sc[j], v[j], sh[j]);
        storerow32(out, (size_t)r * 32u, f32, o);
    }
}

extern "C" void kernel_launch(void* const* d_in, const int* in_sizes, int n_in,
                              void* d_out, int out_size, void* d_ws, size_t ws_size,
                              hipStream_t stream) {
    const void* x   = d_in[0];
    const void* eW1 = d_in[1]; const void* eb1 = d_in[2];
    const void* eW2 = d_in[3]; const void* eb2 = d_in[4];
    const void* eW3 = d_in[5]; const void* eb3 = d_in[6];
    const void* eg  = d_in[7]; const void* ebt = d_in[8];
    const void* nW1 = d_in[9]; const void* nb1 = d_in[10];
    const void* nW2 = d_in[11]; const void* nb2 = d_in[12];
    const void* nW3 = d_in[13]; const void* nb3 = d_in[14];
    const void* ng  = d_in[15]; const void* nbt = d_in[16];

    float* stats = (float*)d_ws;            // 256 floats: [0..63] inplace, [64..127] fwd, [128..191] bwd, [192..255] node
    int* flag = (int*)((char*)d_ws + 1024); // dtype flag: 1 = fp32, 0 = bf16

    hipMemsetAsync(d_ws, 0, 1024, stream);
    detect_kernel<<<dim3(1), dim3(64), 0, stream>>>((const uint*)x, flag);

    dim3 blk(256), grid(2048);
    edge_kernel<0><<<grid, blk, 0, stream>>>(x, eW1, eb1, eW2, eb2, eW3, eb3, flag, stats + 0);
    edge_kernel<1><<<grid, blk, 0, stream>>>(x, eW1, eb1, eW2, eb2, eW3, eb3, flag, stats + 64);
    edge_kernel<2><<<grid, blk, 0, stream>>>(x, eW1, eb1, eW2, eb2, eW3, eb3, flag, stats + 128);
    node_kernel<<<grid, blk, 0, stream>>>(x, eW1, eb1, eW2, eb2, eW3, eb3, eg, ebt,
                                          nW1, nb1, nW2, nb2, nW3, nb3,
                                          flag, stats, stats + 192, d_out);
    finalize_kernel<<<dim3(4096), blk, 0, stream>>>(stats + 192, ng, nbt, flag, d_out);
}

// Round 3
// 13724.551 us; speedup vs baseline: 1.5985x; 1.5985x over previous
//
#include <hip/hip_runtime.h>
#include <stdint.h>

#define NN   2048
#define TTT  512
#define NT   (NN * TTT)          /* 1048576 rows */
#define NTM  (NN * (TTT - 1))    /* 1046528 rows */
#define SLOPE 0.01f
#define BN_EPS 1e-5f

typedef unsigned int uint;

__device__ __forceinline__ float bf2f(uint16_t u) {
    union { uint u32; float f; } v; v.u32 = ((uint)u) << 16; return v.f;
}
__device__ __forceinline__ uint16_t f2bf(float f) {
    union { float f; uint u; } v; v.f = f;
    uint r = v.u + 0x7FFFu + ((v.u >> 16) & 1u);   // RTNE
    return (uint16_t)(r >> 16);
}

template <bool F32>
__device__ __forceinline__ float wv(const void* W, int i) {
    return F32 ? ((const float*)W)[i] : bf2f(((const uint16_t*)W)[i]);
}

template <bool F32>
__device__ __forceinline__ void loadrow16(const void* x, size_t elt, float* f) {
    if (F32) {
        const float4* q = (const float4*)((const float*)x + elt);
        float4 a = q[0], b = q[1], c = q[2], d = q[3];
        f[0]=a.x; f[1]=a.y; f[2]=a.z; f[3]=a.w;
        f[4]=b.x; f[5]=b.y; f[6]=b.z; f[7]=b.w;
        f[8]=c.x; f[9]=c.y; f[10]=c.z; f[11]=c.w;
        f[12]=d.x; f[13]=d.y; f[14]=d.z; f[15]=d.w;
    } else {
        const uint4* q = (const uint4*)((const uint16_t*)x + elt);
        uint4 a = q[0], b = q[1];
        uint w[8] = {a.x, a.y, a.z, a.w, b.x, b.y, b.z, b.w};
#pragma unroll
        for (int i = 0; i < 8; i++) {
            union { uint u; float f; } lo, hi;
            lo.u = w[i] << 16; hi.u = w[i] & 0xFFFF0000u;
            f[2*i] = lo.f; f[2*i+1] = hi.f;
        }
    }
}
template <bool F32>
__device__ __forceinline__ void loadrow32(const void* x, size_t elt, float* f) {
    loadrow16<F32>(x, elt, f); loadrow16<F32>(x, elt + 16, f + 16);
}
template <bool F32>
__device__ __forceinline__ void storerow32(void* out, size_t elt, const float* f) {
    if (F32) {
        float4* q = (float4*)((float*)out + elt);
#pragma unroll
        for (int i = 0; i < 8; i++)
            q[i] = make_float4(f[4*i], f[4*i+1], f[4*i+2], f[4*i+3]);
    } else {
        uint w[16];
#pragma unroll
        for (int i = 0; i < 16; i++)
            w[i] = (uint)f2bf(f[2*i]) | ((uint)f2bf(f[2*i+1]) << 16);
        uint4* q = (uint4*)((uint16_t*)out + elt);
        q[0] = make_uint4(w[0], w[1], w[2], w[3]);
        q[1] = make_uint4(w[4], w[5], w[6], w[7]);
        q[2] = make_uint4(w[8], w[9], w[10], w[11]);
        q[3] = make_uint4(w[12], w[13], w[14], w[15]);
    }
}

// h[j] += sum_i W[i*32+j] * in[i]   (W in LDS fp32, wave-uniform broadcast reads)
template <int K>
__device__ __forceinline__ void dense(const float* W, const float* in, float* h) {
#pragma unroll
    for (int i = 0; i < K; i++) {
        float x = in[i];
        const float4* w4 = (const float4*)(W + i * 32);
#pragma unroll
        for (int j = 0; j < 8; j++) {
            float4 w = w4[j];
            h[4*j+0] = fmaf(w.x, x, h[4*j+0]);
            h[4*j+1] = fmaf(w.y, x, h[4*j+1]);
            h[4*j+2] = fmaf(w.z, x, h[4*j+2]);
            h[4*j+3] = fmaf(w.w, x, h[4*j+3]);
        }
    }
}
__device__ __forceinline__ void lrelu32(float* h) {
#pragma unroll
    for (int j = 0; j < 32; j++) h[j] = fmaxf(h[j], h[j] * SLOPE);
}

// full edge 3-layer MLP; dir: 0 (inplace, uses combined W1c), +1 fwd, -1 bwd
template <bool INPLACE>
__device__ __forceinline__ void edge_mlp(
    const float* sW1, const float* sW1c, const float* sW2, const float* sW3,
    const float* sB1, const float* sB2, const float* sB3,
    const float* xt, const float* xn, float dir, float* o)
{
    float h1[32];
#pragma unroll
    for (int j = 0; j < 32; j++) h1[j] = fmaf(dir, sW1[1024 + j], sB1[j]);
    if (INPLACE) {
        dense<16>(sW1c, xt, h1);
    } else {
        dense<16>(sW1, xt, h1);
        dense<16>(sW1 + 512, xn, h1);
    }
    lrelu32(h1);
    float h2[32];
#pragma unroll
    for (int j = 0; j < 32; j++) h2[j] = sB2[j];
    dense<32>(sW2, h1, h2);
    lrelu32(h2);
#pragma unroll
    for (int j = 0; j < 32; j++) o[j] = sB3[j];
    dense<32>(sW3, h2, o);
}

// wave butterfly reduce of v and v^2 per channel -> LDS atomics (1 lane each)
__device__ __forceinline__ void stats_accum(const float* v, float* dst, int lane) {
#pragma unroll
    for (int j = 0; j < 32; j++) {
        float s = v[j], q = v[j] * v[j];
#pragma unroll
        for (int m = 1; m < 64; m <<= 1) { s += __shfl_xor(s, m, 64); q += __shfl_xor(q, m, 64); }
        if (lane == j) atomicAdd(&dst[j], s);
        if (lane == 32 + j) atomicAdd(&dst[32 + j], q);
    }
}

// ---------------- dtype detect: 1 = fp32, 0 = bf16 ----------------
__global__ void detect_kernel(const uint* __restrict__ x, int* __restrict__ flag) {
    __shared__ int cnt;
    if (threadIdx.x == 0) cnt = 0;
    __syncthreads();
    uint w = x[threadIdx.x];
    uint e = (w >> 7) & 0xFFu;
    if (e >= 110u && e <= 134u) atomicAdd(&cnt, 1);
    __syncthreads();
    if (threadIdx.x == 0) flag[0] = (cnt < 32) ? 1 : 0;
}

// ---------------- pass 1: edge stats (all 3 branches per row) ----------------
template <bool F32>
__global__ __launch_bounds__(256) void edge_stats_kernel(
    const void* __restrict__ x,
    const void* __restrict__ W1, const void* __restrict__ b1,
    const void* __restrict__ W2, const void* __restrict__ b2,
    const void* __restrict__ W3, const void* __restrict__ b3,
    const int* __restrict__ flag, float* __restrict__ gstats /*192*/)
{
    if ((flag[0] != 0) != F32) return;
    __shared__ __align__(16) float sW1[1056];
    __shared__ __align__(16) float sW1c[512];
    __shared__ __align__(16) float sW2[1024];
    __shared__ __align__(16) float sW3[1024];
    __shared__ float sB1[32], sB2[32], sB3[32];
    __shared__ float sSt[192];
    const int tid = threadIdx.x;
    const int lane = tid & 63;

    for (int i = tid; i < 1056; i += 256) sW1[i] = wv<F32>(W1, i);
    for (int i = tid; i < 512; i += 256) sW1c[i] = wv<F32>(W1, i) + wv<F32>(W1, 512 + i);
    for (int i = tid; i < 1024; i += 256) { sW2[i] = wv<F32>(W2, i); sW3[i] = wv<F32>(W3, i); }
    if (tid < 32) { sB1[tid] = wv<F32>(b1, tid); sB2[tid] = wv<F32>(b2, tid); sB3[tid] = wv<F32>(b3, tid); }
    if (tid < 192) sSt[tid] = 0.f;
    __syncthreads();

    const uint r = blockIdx.x * 256u + (uint)tid;   // grid covers NT exactly
    const uint t = r & 511u;
    float xt[16]; loadrow16<F32>(x, (size_t)r << 4, xt);
    float o[32];

    // inplace
    edge_mlp<true>(sW1, sW1c, sW2, sW3, sB1, sB2, sB3, xt, xt, 0.f, o);
    stats_accum(o, &sSt[0], lane);

    // fwd: neighbor t-1, valid t>0
    {
        const float vf = (t > 0u) ? 1.f : 0.f;
        const uint rn = (t > 0u) ? r - 1u : r;
        float xn[16]; loadrow16<F32>(x, (size_t)rn << 4, xn);
        edge_mlp<false>(sW1, sW1c, sW2, sW3, sB1, sB2, sB3, xt, xn, 1.f, o);
#pragma unroll
        for (int j = 0; j < 32; j++) o[j] *= vf;
        stats_accum(o, &sSt[64], lane);
    }
    // bwd: neighbor t+1, valid t<511
    {
        const float vf = (t < 511u) ? 1.f : 0.f;
        const uint rn = (t < 511u) ? r + 1u : r;
        float xn[16]; loadrow16<F32>(x, (size_t)rn << 4, xn);
        edge_mlp<false>(sW1, sW1c, sW2, sW3, sB1, sB2, sB3, xt, xn, -1.f, o);
#pragma unroll
        for (int j = 0; j < 32; j++) o[j] *= vf;
        stats_accum(o, &sSt[128], lane);
    }
    __syncthreads();
    if (tid < 192) atomicAdd(&gstats[tid], sSt[tid]);
}

// ---------------- pass 2: node (recompute branches, aggregate, node MLP) ----------------
template <bool F32>
__global__ __launch_bounds__(256) void node_kernel(
    const void* __restrict__ x,
    const void* __restrict__ eW1, const void* __restrict__ eb1,
    const void* __restrict__ eW2, const void* __restrict__ eb2,
    const void* __restrict__ eW3, const void* __restrict__ eb3,
    const void* __restrict__ egamma, const void* __restrict__ ebeta,
    const void* __restrict__ nW1, const void* __restrict__ nb1,
    const void* __restrict__ nW2, const void* __restrict__ nb2,
    const void* __restrict__ nW3, const void* __restrict__ nb3,
    const int* __restrict__ flag,
    const float* __restrict__ gstats_edge, float* __restrict__ gstats_node,
    void* __restrict__ out)
{
    if ((flag[0] != 0) != F32) return;
    __shared__ __align__(16) float sEW1[1056];
    __shared__ __align__(16) float sEW1c[512];
    __shared__ __align__(16) float sEW2[1024];
    __shared__ __align__(16) float sEW3[1024];
    __shared__ __align__(16) float sNW1[1024];
    __shared__ __align__(16) float sNW2[1024];
    __shared__ __align__(16) float sNW3[1024];
    __shared__ float sEB1[32], sEB2[32], sEB3[32];
    __shared__ float sNB1[32], sNB2[32], sNB3[32];
    __shared__ float sAff[192];   // per branch: scale[32], shift[32]
    __shared__ float sSt[64];
    const int tid = threadIdx.x;
    const int lane = tid & 63;

    for (int i = tid; i < 1056; i += 256) sEW1[i] = wv<F32>(eW1, i);
    for (int i = tid; i < 512; i += 256) sEW1c[i] = wv<F32>(eW1, i) + wv<F32>(eW1, 512 + i);
    for (int i = tid; i < 1024; i += 256) {
        sEW2[i] = wv<F32>(eW2, i); sEW3[i] = wv<F32>(eW3, i);
        sNW1[i] = wv<F32>(nW1, i); sNW2[i] = wv<F32>(nW2, i); sNW3[i] = wv<F32>(nW3, i);
    }
    if (tid < 32) {
        sEB1[tid] = wv<F32>(eb1, tid); sEB2[tid] = wv<F32>(eb2, tid); sEB3[tid] = wv<F32>(eb3, tid);
        sNB1[tid] = wv<F32>(nb1, tid); sNB2[tid] = wv<F32>(nb2, tid); sNB3[tid] = wv<F32>(nb3, tid);
        float g = wv<F32>(egamma, tid), be = wv<F32>(ebeta, tid);
#pragma unroll
        for (int br = 0; br < 3; br++) {
            float cnt = (br == 0) ? (float)NT : (float)NTM;
            float s = gstats_edge[br * 64 + tid], q = gstats_edge[br * 64 + 32 + tid];
            float mu = s / cnt;
            float var = q / cnt - mu * mu;
            float sc = g * rsqrtf(var + BN_EPS);
            sAff[br * 64 + tid] = sc;
            sAff[br * 64 + 32 + tid] = be - mu * sc;
        }
    }
    if (tid < 64) sSt[tid] = 0.f;
    __syncthreads();

    const uint r = blockIdx.x * 256u + (uint)tid;
    const uint t = r & 511u;
    float xt[16]; loadrow16<F32>(x, (size_t)r << 4, xt);
    float agg[32], o[32];

    // inplace
    edge_mlp<true>(sEW1, sEW1c, sEW2, sEW3, sEB1, sEB2, sEB3, xt, xt, 0.f, o);
#pragma unroll
    for (int j = 0; j < 32; j++) agg[j] = fmaf(sAff[j], o[j], sAff[32 + j]);

    // fwd
    {
        const float vf = (t > 0u) ? 1.f : 0.f;
        const uint rn = (t > 0u) ? r - 1u : r;
        float xn[16]; loadrow16<F32>(x, (size_t)rn << 4, xn);
        edge_mlp<false>(sEW1, sEW1c, sEW2, sEW3, sEB1, sEB2, sEB3, xt, xn, 1.f, o);
#pragma unroll
        for (int j = 0; j < 32; j++) agg[j] += vf * fmaf(sAff[64 + j], o[j], sAff[96 + j]);
    }
    // bwd
    {
        const float vf = (t < 511u) ? 1.f : 0.f;
        const uint rn = (t < 511u) ? r + 1u : r;
        float xn[16]; loadrow16<F32>(x, (size_t)rn << 4, xn);
        edge_mlp<false>(sEW1, sEW1c, sEW2, sEW3, sEB1, sEB2, sEB3, xt, xn, -1.f, o);
#pragma unroll
        for (int j = 0; j < 32; j++) agg[j] += vf * fmaf(sAff[128 + j], o[j], sAff[160 + j]);
    }

    // node MLP
    float g1[32];
#pragma unroll
    for (int j = 0; j < 32; j++) g1[j] = sNB1[j];
    dense<32>(sNW1, agg, g1);
    lrelu32(g1);
    float g2[32];
#pragma unroll
    for (int j = 0; j < 32; j++) g2[j] = sNB2[j];
    dense<32>(sNW2, g1, g2);
    lrelu32(g2);
    float g3[32];
#pragma unroll
    for (int j = 0; j < 32; j++) g3[j] = sNB3[j];
    dense<32>(sNW3, g2, g3);

    storerow32<F32>(out, (size_t)r * 32u, g3);
    stats_accum(g3, sSt, lane);
    __syncthreads();
    if (tid < 64) atomicAdd(&gstats_node[tid], sSt[tid]);
}

// ---------------- pass 3: in-place node BN affine ----------------
template <bool F32>
__global__ __launch_bounds__(256) void finalize_kernel(
    const float* __restrict__ gstats_node,
    const void* __restrict__ ngamma, const void* __restrict__ nbeta,
    const int* __restrict__ flag, void* __restrict__ out)
{
    if ((flag[0] != 0) != F32) return;
    __shared__ float sc[32], sh[32];
    const int tid = threadIdx.x;
    if (tid < 32) {
        float s = gstats_node[tid], q = gstats_node[32 + tid];
        float mu = s / (float)NT;
        float var = q / (float)NT - mu * mu;
        float k = wv<F32>(ngamma, tid) * rsqrtf(var + BN_EPS);
        sc[tid] = k; sh[tid] = wv<F32>(nbeta, tid) - mu * k;
    }
    __syncthreads();
    const uint r = blockIdx.x * 256u + (uint)tid;
    float v[32]; loadrow32<F32>(out, (size_t)r * 32u, v);
    float o[32];
#pragma unroll
    for (int j = 0; j < 32; j++) o[j] = fmaf(sc[j], v[j], sh[j]);
    storerow32<F32>(out, (size_t)r * 32u, o);
}

extern "C" void kernel_launch(void* const* d_in, const int* in_sizes, int n_in,
                              void* d_out, int out_size, void* d_ws, size_t ws_size,
                              hipStream_t stream) {
    const void* x   = d_in[0];
    const void* eW1 = d_in[1]; const void* eb1 = d_in[2];
    const void* eW2 = d_in[3]; const void* eb2 = d_in[4];
    const void* eW3 = d_in[5]; const void* eb3 = d_in[6];
    const void* eg  = d_in[7]; const void* ebt = d_in[8];
    const void* nW1 = d_in[9]; const void* nb1 = d_in[10];
    const void* nW2 = d_in[11]; const void* nb2 = d_in[12];
    const void* nW3 = d_in[13]; const void* nb3 = d_in[14];
    const void* ng  = d_in[15]; const void* nbt = d_in[16];

    float* stats = (float*)d_ws;            // [0..191] edge stats, [192..255] node stats
    int* flag = (int*)((char*)d_ws + 1024); // dtype flag: 1 = fp32, 0 = bf16

    hipMemsetAsync(d_ws, 0, 1024, stream);
    detect_kernel<<<dim3(1), dim3(64), 0, stream>>>((const uint*)x, flag);

    dim3 blk(256), grid(NT / 256);
    edge_stats_kernel<true><<<grid, blk, 0, stream>>>(x, eW1, eb1, eW2, eb2, eW3, eb3, flag, stats);
    edge_stats_kernel<false><<<grid, blk, 0, stream>>>(x, eW1, eb1, eW2, eb2, eW3, eb3, flag, stats);
    node_kernel<true><<<grid, blk, 0, stream>>>(x, eW1, eb1, eW2, eb2, eW3, eb3, eg, ebt,
                                                nW1, nb1, nW2, nb2, nW3, nb3,
                                                flag, stats, stats + 192, d_out);
    node_kernel<false><<<grid, blk, 0, stream>>>(x, eW1, eb1, eW2, eb2, eW3, eb3, eg, ebt,
                                                 nW1, nb1, nW2, nb2, nW3, nb3,
                                                 flag, stats, stats + 192, d_out);
    finalize_kernel<true><<<grid, blk, 0, stream>>>(stats + 192, ng, nbt, flag, d_out);
    finalize_kernel<false><<<grid, blk, 0, stream>>>(stats + 192, ng, nbt, flag, d_out);
}

// Round 4
// 1824.098 us; speedup vs baseline: 12.0271x; 7.5240x over previous
//
#include <hip/hip_runtime.h>
#include <stdint.h>

#define NN   2048
#define TTT  512
#define NT   (NN * TTT)          /* 1048576 rows */
#define NTM  (NN * (TTT - 1))    /* 1046528 rows */
#define SLOPE 0.01f
#define BN_EPS 1e-5f

typedef unsigned int uint;

__device__ __forceinline__ float bf2f(uint16_t u) {
    union { uint u32; float f; } v; v.u32 = ((uint)u) << 16; return v.f;
}
__device__ __forceinline__ uint16_t f2bf(float f) {
    union { float f; uint u; } v; v.f = f;
    uint r = v.u + 0x7FFFu + ((v.u >> 16) & 1u);   // RTNE
    return (uint16_t)(r >> 16);
}

template <bool F32>
__device__ __forceinline__ float wv(const void* W, int i) {
    return F32 ? ((const float*)W)[i] : bf2f(((const uint16_t*)W)[i]);
}

template <bool F32>
__device__ __forceinline__ void loadrow16(const void* x, size_t elt, float* f) {
    if (F32) {
        const float4* q = (const float4*)((const float*)x + elt);
        float4 a = q[0], b = q[1], c = q[2], d = q[3];
        f[0]=a.x; f[1]=a.y; f[2]=a.z; f[3]=a.w;
        f[4]=b.x; f[5]=b.y; f[6]=b.z; f[7]=b.w;
        f[8]=c.x; f[9]=c.y; f[10]=c.z; f[11]=c.w;
        f[12]=d.x; f[13]=d.y; f[14]=d.z; f[15]=d.w;
    } else {
        const uint4* q = (const uint4*)((const uint16_t*)x + elt);
        uint4 a = q[0], b = q[1];
        uint w[8] = {a.x, a.y, a.z, a.w, b.x, b.y, b.z, b.w};
#pragma unroll
        for (int i = 0; i < 8; i++) {
            union { uint u; float f; } lo, hi;
            lo.u = w[i] << 16; hi.u = w[i] & 0xFFFF0000u;
            f[2*i] = lo.f; f[2*i+1] = hi.f;
        }
    }
}
template <bool F32>
__device__ __forceinline__ void loadrow32(const void* x, size_t elt, float* f) {
    loadrow16<F32>(x, elt, f); loadrow16<F32>(x, elt + 16, f + 16);
}
template <bool F32>
__device__ __forceinline__ void storerow32(void* out, size_t elt, const float* f) {
    if (F32) {
        float4* q = (float4*)((float*)out + elt);
#pragma unroll
        for (int i = 0; i < 8; i++)
            q[i] = make_float4(f[4*i], f[4*i+1], f[4*i+2], f[4*i+3]);
    } else {
        uint w[16];
#pragma unroll
        for (int i = 0; i < 16; i++)
            w[i] = (uint)f2bf(f[2*i]) | ((uint)f2bf(f[2*i+1]) << 16);
        uint4* q = (uint4*)((uint16_t*)out + elt);
        q[0] = make_uint4(w[0], w[1], w[2], w[3]);
        q[1] = make_uint4(w[4], w[5], w[6], w[7]);
        q[2] = make_uint4(w[8], w[9], w[10], w[11]);
        q[3] = make_uint4(w[12], w[13], w[14], w[15]);
    }
}

// h[j] += sum_i W[i*32+j] * in[i]   (W in LDS fp32, wave-uniform broadcast reads).
// unroll 2 on the K loop: loop back-edges fence the scheduler so at most
// 2x8 ds_read_b128 are in flight -> no VGPR-pressure explosion / scratch spill.
template <int K>
__device__ __forceinline__ void dense(const float* W, const float* in, float* h) {
#pragma unroll 2
    for (int i = 0; i < K; i++) {
        float x = in[i];
        const float4* w4 = (const float4*)(W + i * 32);
#pragma unroll
        for (int j = 0; j < 8; j++) {
            float4 w = w4[j];
            h[4*j+0] = fmaf(w.x, x, h[4*j+0]);
            h[4*j+1] = fmaf(w.y, x, h[4*j+1]);
            h[4*j+2] = fmaf(w.z, x, h[4*j+2]);
            h[4*j+3] = fmaf(w.w, x, h[4*j+3]);
        }
    }
}
__device__ __forceinline__ void lrelu32(float* h) {
#pragma unroll
    for (int j = 0; j < 32; j++) h[j] = fmaxf(h[j], h[j] * SLOPE);
}

// full edge 3-layer MLP; dir: 0 (inplace, uses combined W1c), +1 fwd, -1 bwd
template <bool INPLACE>
__device__ __forceinline__ void edge_mlp(
    const float* sW1, const float* sW1c, const float* sW2, const float* sW3,
    const float* sB1, const float* sB2, const float* sB3,
    const float* xt, const float* xn, float dir, float* o)
{
    float h1[32];
#pragma unroll
    for (int j = 0; j < 32; j++) h1[j] = fmaf(dir, sW1[1024 + j], sB1[j]);
    if (INPLACE) {
        dense<16>(sW1c, xt, h1);
    } else {
        dense<16>(sW1, xt, h1);
        dense<16>(sW1 + 512, xn, h1);
    }
    lrelu32(h1);
    float h2[32];
#pragma unroll
    for (int j = 0; j < 32; j++) h2[j] = sB2[j];
    dense<32>(sW2, h1, h2);
    lrelu32(h2);
#pragma unroll
    for (int j = 0; j < 32; j++) o[j] = sB3[j];
    dense<32>(sW3, h2, o);
}

// wave butterfly reduce of v and v^2 per channel -> LDS atomics (1 lane each)
__device__ __forceinline__ void stats_accum(const float* v, float* dst, int lane) {
#pragma unroll
    for (int j = 0; j < 32; j++) {
        float s = v[j], q = v[j] * v[j];
#pragma unroll
        for (int m = 1; m < 64; m <<= 1) { s += __shfl_xor(s, m, 64); q += __shfl_xor(q, m, 64); }
        if (lane == j) atomicAdd(&dst[j], s);
        if (lane == 32 + j) atomicAdd(&dst[32 + j], q);
    }
}

// ---------------- dtype detect: 1 = fp32, 0 = bf16 ----------------
__global__ void detect_kernel(const uint* __restrict__ x, int* __restrict__ flag) {
    __shared__ int cnt;
    if (threadIdx.x == 0) cnt = 0;
    __syncthreads();
    uint w = x[threadIdx.x];
    uint e = (w >> 7) & 0xFFu;
    if (e >= 110u && e <= 134u) atomicAdd(&cnt, 1);
    __syncthreads();
    if (threadIdx.x == 0) flag[0] = (cnt < 32) ? 1 : 0;
}

// ---------------- pass 1: edge stats (all 3 branches per row) ----------------
template <bool F32>
__global__ __launch_bounds__(256) void edge_stats_kernel(
    const void* __restrict__ x,
    const void* __restrict__ W1, const void* __restrict__ b1,
    const void* __restrict__ W2, const void* __restrict__ b2,
    const void* __restrict__ W3, const void* __restrict__ b3,
    const int* __restrict__ flag, float* __restrict__ gstats /*192*/)
{
    if ((flag[0] != 0) != F32) return;
    __shared__ __align__(16) float sW1[1056];
    __shared__ __align__(16) float sW1c[512];
    __shared__ __align__(16) float sW2[1024];
    __shared__ __align__(16) float sW3[1024];
    __shared__ float sB1[32], sB2[32], sB3[32];
    __shared__ float sSt[192];
    const int tid = threadIdx.x;
    const int lane = tid & 63;

    for (int i = tid; i < 1056; i += 256) sW1[i] = wv<F32>(W1, i);
    for (int i = tid; i < 512; i += 256) sW1c[i] = wv<F32>(W1, i) + wv<F32>(W1, 512 + i);
    for (int i = tid; i < 1024; i += 256) { sW2[i] = wv<F32>(W2, i); sW3[i] = wv<F32>(W3, i); }
    if (tid < 32) { sB1[tid] = wv<F32>(b1, tid); sB2[tid] = wv<F32>(b2, tid); sB3[tid] = wv<F32>(b3, tid); }
    if (tid < 192) sSt[tid] = 0.f;
    __syncthreads();

    const uint r = blockIdx.x * 256u + (uint)tid;   // grid covers NT exactly
    const uint t = r & 511u;
    float xt[16]; loadrow16<F32>(x, (size_t)r << 4, xt);
    float o[32];

    // inplace
    edge_mlp<true>(sW1, sW1c, sW2, sW3, sB1, sB2, sB3, xt, xt, 0.f, o);
    stats_accum(o, &sSt[0], lane);

    // fwd: neighbor t-1, valid t>0
    {
        const float vf = (t > 0u) ? 1.f : 0.f;
        const uint rn = (t > 0u) ? r - 1u : r;
        float xn[16]; loadrow16<F32>(x, (size_t)rn << 4, xn);
        edge_mlp<false>(sW1, sW1c, sW2, sW3, sB1, sB2, sB3, xt, xn, 1.f, o);
#pragma unroll
        for (int j = 0; j < 32; j++) o[j] *= vf;
        stats_accum(o, &sSt[64], lane);
    }
    // bwd: neighbor t+1, valid t<511
    {
        const float vf = (t < 511u) ? 1.f : 0.f;
        const uint rn = (t < 511u) ? r + 1u : r;
        float xn[16]; loadrow16<F32>(x, (size_t)rn << 4, xn);
        edge_mlp<false>(sW1, sW1c, sW2, sW3, sB1, sB2, sB3, xt, xn, -1.f, o);
#pragma unroll
        for (int j = 0; j < 32; j++) o[j] *= vf;
        stats_accum(o, &sSt[128], lane);
    }
    __syncthreads();
    if (tid < 192) atomicAdd(&gstats[tid], sSt[tid]);
}

// ---------------- pass 2: node (recompute branches, aggregate, node MLP) ----------------
template <bool F32>
__global__ __launch_bounds__(256) void node_kernel(
    const void* __restrict__ x,
    const void* __restrict__ eW1, const void* __restrict__ eb1,
    const void* __restrict__ eW2, const void* __restrict__ eb2,
    const void* __restrict__ eW3, const void* __restrict__ eb3,
    const void* __restrict__ egamma, const void* __restrict__ ebeta,
    const void* __restrict__ nW1, const void* __restrict__ nb1,
    const void* __restrict__ nW2, const void* __restrict__ nb2,
    const void* __restrict__ nW3, const void* __restrict__ nb3,
    const int* __restrict__ flag,
    const float* __restrict__ gstats_edge, float* __restrict__ gstats_node,
    void* __restrict__ out)
{
    if ((flag[0] != 0) != F32) return;
    __shared__ __align__(16) float sEW1[1056];
    __shared__ __align__(16) float sEW1c[512];
    __shared__ __align__(16) float sEW2[1024];
    __shared__ __align__(16) float sEW3[1024];
    __shared__ __align__(16) float sNW1[1024];
    __shared__ __align__(16) float sNW2[1024];
    __shared__ __align__(16) float sNW3[1024];
    __shared__ float sEB1[32], sEB2[32], sEB3[32];
    __shared__ float sNB1[32], sNB2[32], sNB3[32];
    __shared__ float sAff[192];   // per branch: scale[32], shift[32]
    __shared__ float sSt[64];
    const int tid = threadIdx.x;
    const int lane = tid & 63;

    for (int i = tid; i < 1056; i += 256) sEW1[i] = wv<F32>(eW1, i);
    for (int i = tid; i < 512; i += 256) sEW1c[i] = wv<F32>(eW1, i) + wv<F32>(eW1, 512 + i);
    for (int i = tid; i < 1024; i += 256) {
        sEW2[i] = wv<F32>(eW2, i); sEW3[i] = wv<F32>(eW3, i);
        sNW1[i] = wv<F32>(nW1, i); sNW2[i] = wv<F32>(nW2, i); sNW3[i] = wv<F32>(nW3, i);
    }
    if (tid < 32) {
        sEB1[tid] = wv<F32>(eb1, tid); sEB2[tid] = wv<F32>(eb2, tid); sEB3[tid] = wv<F32>(eb3, tid);
        sNB1[tid] = wv<F32>(nb1, tid); sNB2[tid] = wv<F32>(nb2, tid); sNB3[tid] = wv<F32>(nb3, tid);
        float g = wv<F32>(egamma, tid), be = wv<F32>(ebeta, tid);
#pragma unroll
        for (int br = 0; br < 3; br++) {
            float cnt = (br == 0) ? (float)NT : (float)NTM;
            float s = gstats_edge[br * 64 + tid], q = gstats_edge[br * 64 + 32 + tid];
            float mu = s / cnt;
            float var = q / cnt - mu * mu;
            float sc = g * rsqrtf(var + BN_EPS);
            sAff[br * 64 + tid] = sc;
            sAff[br * 64 + 32 + tid] = be - mu * sc;
        }
    }
    if (tid < 64) sSt[tid] = 0.f;
    __syncthreads();

    const uint r = blockIdx.x * 256u + (uint)tid;
    const uint t = r & 511u;
    float xt[16]; loadrow16<F32>(x, (size_t)r << 4, xt);
    float agg[32], o[32];

    // inplace
    edge_mlp<true>(sEW1, sEW1c, sEW2, sEW3, sEB1, sEB2, sEB3, xt, xt, 0.f, o);
#pragma unroll
    for (int j = 0; j < 32; j++) agg[j] = fmaf(sAff[j], o[j], sAff[32 + j]);

    // fwd
    {
        const float vf = (t > 0u) ? 1.f : 0.f;
        const uint rn = (t > 0u) ? r - 1u : r;
        float xn[16]; loadrow16<F32>(x, (size_t)rn << 4, xn);
        edge_mlp<false>(sEW1, sEW1c, sEW2, sEW3, sEB1, sEB2, sEB3, xt, xn, 1.f, o);
#pragma unroll
        for (int j = 0; j < 32; j++) agg[j] += vf * fmaf(sAff[64 + j], o[j], sAff[96 + j]);
    }
    // bwd
    {
        const float vf = (t < 511u) ? 1.f : 0.f;
        const uint rn = (t < 511u) ? r + 1u : r;
        float xn[16]; loadrow16<F32>(x, (size_t)rn << 4, xn);
        edge_mlp<false>(sEW1, sEW1c, sEW2, sEW3, sEB1, sEB2, sEB3, xt, xn, -1.f, o);
#pragma unroll
        for (int j = 0; j < 32; j++) agg[j] += vf * fmaf(sAff[128 + j], o[j], sAff[160 + j]);
    }

    // node MLP
    float g1[32];
#pragma unroll
    for (int j = 0; j < 32; j++) g1[j] = sNB1[j];
    dense<32>(sNW1, agg, g1);
    lrelu32(g1);
    float g2[32];
#pragma unroll
    for (int j = 0; j < 32; j++) g2[j] = sNB2[j];
    dense<32>(sNW2, g1, g2);
    lrelu32(g2);
    float g3[32];
#pragma unroll
    for (int j = 0; j < 32; j++) g3[j] = sNB3[j];
    dense<32>(sNW3, g2, g3);

    storerow32<F32>(out, (size_t)r * 32u, g3);
    stats_accum(g3, sSt, lane);
    __syncthreads();
    if (tid < 64) atomicAdd(&gstats_node[tid], sSt[tid]);
}

// ---------------- pass 3: in-place node BN affine ----------------
template <bool F32>
__global__ __launch_bounds__(256) void finalize_kernel(
    const float* __restrict__ gstats_node,
    const void* __restrict__ ngamma, const void* __restrict__ nbeta,
    const int* __restrict__ flag, void* __restrict__ out)
{
    if ((flag[0] != 0) != F32) return;
    __shared__ float sc[32], sh[32];
    const int tid = threadIdx.x;
    if (tid < 32) {
        float s = gstats_node[tid], q = gstats_node[32 + tid];
        float mu = s / (float)NT;
        float var = q / (float)NT - mu * mu;
        float k = wv<F32>(ngamma, tid) * rsqrtf(var + BN_EPS);
        sc[tid] = k; sh[tid] = wv<F32>(nbeta, tid) - mu * k;
    }
    __syncthreads();
    const uint r = blockIdx.x * 256u + (uint)tid;
    float v[32]; loadrow32<F32>(out, (size_t)r * 32u, v);
    float o[32];
#pragma unroll
    for (int j = 0; j < 32; j++) o[j] = fmaf(sc[j], v[j], sh[j]);
    storerow32<F32>(out, (size_t)r * 32u, o);
}

extern "C" void kernel_launch(void* const* d_in, const int* in_sizes, int n_in,
                              void* d_out, int out_size, void* d_ws, size_t ws_size,
                              hipStream_t stream) {
    const void* x   = d_in[0];
    const void* eW1 = d_in[1]; const void* eb1 = d_in[2];
    const void* eW2 = d_in[3]; const void* eb2 = d_in[4];
    const void* eW3 = d_in[5]; const void* eb3 = d_in[6];
    const void* eg  = d_in[7]; const void* ebt = d_in[8];
    const void* nW1 = d_in[9]; const void* nb1 = d_in[10];
    const void* nW2 = d_in[11]; const void* nb2 = d_in[12];
    const void* nW3 = d_in[13]; const void* nb3 = d_in[14];
    const void* ng  = d_in[15]; const void* nbt = d_in[16];

    float* stats = (float*)d_ws;            // [0..191] edge stats, [192..255] node stats
    int* flag = (int*)((char*)d_ws + 1024); // dtype flag: 1 = fp32, 0 = bf16

    hipMemsetAsync(d_ws, 0, 1024, stream);
    detect_kernel<<<dim3(1), dim3(64), 0, stream>>>((const uint*)x, flag);

    dim3 blk(256), grid(NT / 256);
    edge_stats_kernel<true><<<grid, blk, 0, stream>>>(x, eW1, eb1, eW2, eb2, eW3, eb3, flag, stats);
    edge_stats_kernel<false><<<grid, blk, 0, stream>>>(x, eW1, eb1, eW2, eb2, eW3, eb3, flag, stats);
    node_kernel<true><<<grid, blk, 0, stream>>>(x, eW1, eb1, eW2, eb2, eW3, eb3, eg, ebt,
                                                nW1, nb1, nW2, nb2, nW3, nb3,
                                                flag, stats, stats + 192, d_out);
    node_kernel<false><<<grid, blk, 0, stream>>>(x, eW1, eb1, eW2, eb2, eW3, eb3, eg, ebt,
                                                 nW1, nb1, nW2, nb2, nW3, nb3,
                                                 flag, stats, stats + 192, d_out);
    finalize_kernel<true><<<grid, blk, 0, stream>>>(stats + 192, ng, nbt, flag, d_out);
    finalize_kernel<false><<<grid, blk, 0, stream>>>(stats + 192, ng, nbt, flag, d_out);
}